// Round 1
// baseline (26364.371 us; speedup 1.0000x reference)
//
#include <hip/hip_runtime.h>
#include <cstddef>

#define B_TOT   4096
#define T_SEQ   64
#define F_IN    32
#define C_CTY   64
#define L_LAT   256
#define W_HID   512
#define NT_OUT  8
#define SUBSTEPS 10

#define MB    32                 // batch rows per block
#define NBLK  (B_TOT / MB)       // 128 blocks
#define NTHR  512                // 8 waves

// LDS row strides (padded: stride*elemsize % 128B == 16B -> 2-way bank aliasing only)
#define YS 260    // fp32 y
#define KS 264    // bf16 k bufs
#define AS 520    // bf16 activations
#define GS 1032   // bf16 GRU gate sums
#define XS 296    // bf16 GRU [h | x] input

typedef __bf16 bf16;
typedef __bf16 bf16x8 __attribute__((ext_vector_type(8)));
typedef __bf16 bf16x4 __attribute__((ext_vector_type(4)));
typedef float  f32x4  __attribute__((ext_vector_type(4)));

// Tsit5 tableau
constexpr float A21 = 0.161f;
constexpr float A31 = -0.008480655492356989f, A32 = 0.335480655492357f;
constexpr float A41 = 2.8971530571054935f, A42 = -6.359448489975075f, A43 = 4.362295432869581f;
constexpr float A51 = 5.325864828439257f, A52 = -11.748883564062828f, A53 = 7.4955393428898365f, A54 = -0.09249506636175525f;
constexpr float A61 = 5.86145544294642f, A62 = -12.92096931784711f, A63 = 8.159367898576159f, A64 = -0.071584973281401f, A65 = -0.028269050394068383f;
constexpr float BC1 = 0.09646076681806523f, BC2 = 0.01f, BC3 = 0.4798896504144996f;
constexpr float BC4 = 1.379008574103742f, BC5 = -3.290069515436081f, BC6 = 2.324710524099774f;
constexpr float DT = 0.1f;

constexpr float TC1[5] = {0, 0, 0, 0, 0};
constexpr float TC2[5] = {A21, 0, 0, 0, 0};
constexpr float TC3[5] = {A31, A32, 0, 0, 0};
constexpr float TC4[5] = {A41, A42, A43, 0, 0};
constexpr float TC5[5] = {A51, A52, A53, A54, 0};
constexpr float TC6[5] = {A61, A62, A63, A64, A65};

struct SmemODE {
    float Y[MB * YS];                       // 33,280 B (fp32 state; also GRU h)
    bf16  Kb[5][MB * KS];                   // 84,480 B (k1..k5)
    bf16  Act[MB * AS];                     // 33,280 B (y_stage / h1 / h2)
    float Wdec[NT_OUT * L_LAT];
    float bdec[NT_OUT];
    int   cty[MB];
};
struct SmemGRU {
    float Y[MB * YS];
    bf16  hhih[MB * GS];                    // 66,048 B (S_r | S_z | inn | hn)
    char  pad1[84480 - MB * GS * 2];
    bf16  hx[MB * XS];                      // 18,944 B ([h_bf16 | x_t])
    char  pad2[33280 - MB * XS * 2];
    float Wdec[NT_OUT * L_LAT];
    float bdec[NT_OUT];
    int   cty[MB];
};
union Smem { SmemODE o; SmemGRU g; };
static_assert(sizeof(Smem) <= 160 * 1024, "LDS overflow");
static_assert(offsetof(SmemODE, Wdec) == offsetof(SmemGRU, Wdec), "layout mismatch");
static_assert(offsetof(SmemODE, cty) == offsetof(SmemGRU, cty), "layout mismatch");

__device__ __forceinline__ float bf2f(bf16 x) { return (float)x; }
__device__ __forceinline__ bf16  f2bf(float x) { return (bf16)x; }
__device__ __forceinline__ float elu_f(float x) { return x > 0.f ? x : __expf(x) - 1.f; }
__device__ __forceinline__ float sigm_f(float x) { return 1.f / (1.f + __expf(-x)); }
__device__ __forceinline__ float tanh_fast(float x) { return 1.f - 2.f / (__expf(2.f * x) + 1.f); }

__device__ __forceinline__ f32x4 MFMA(bf16x8 a, bf16x8 b, f32x4 c) {
    return __builtin_amdgcn_mfma_f32_16x16x32_bf16(a, b, c, 0, 0, 0);
}

// Build Act[:, :256] = bf16(Y + DT * sum_j cf[j] * Kb[j]); NS = number of k terms.
template<int NS>
__device__ __forceinline__ void build_stage(Smem& sm, int tid, const float* cf) {
    const int row = tid >> 4;
    const int cb  = (tid & 15) << 4;
    #pragma unroll
    for (int c = 0; c < 16; c += 4) {
        f32x4 acc = *(const f32x4*)&sm.o.Y[row * YS + cb + c];
        #pragma unroll
        for (int j = 0; j < NS; ++j) {
            bf16x4 kv = *(const bf16x4*)&sm.o.Kb[j][row * KS + cb + c];
            const float cj = DT * cf[j];
            acc[0] += cj * bf2f(kv[0]); acc[1] += cj * bf2f(kv[1]);
            acc[2] += cj * bf2f(kv[2]); acc[3] += cj * bf2f(kv[3]);
        }
        bf16x4 o;
        o[0] = f2bf(acc[0]); o[1] = f2bf(acc[1]); o[2] = f2bf(acc[2]); o[3] = f2bf(acc[3]);
        *(bf16x4*)&sm.o.Act[row * AS + cb + c] = o;
    }
}

// One MLP eval: Act[:, :256] -> f; writes k to kdst (bf16), or if kdst==nullptr
// (stage 6) accumulates Y += DT*BC6*f. Assumes synced on entry; synced on exit.
__device__ void eval_f(Smem& sm,
                       const bf16* __restrict__ W0b, const bf16* __restrict__ W1b,
                       const bf16* __restrict__ W2b,
                       const float* __restrict__ b0, const float* __restrict__ b1,
                       const float* __restrict__ b2,
                       int wave, int lane, bf16* kdst) {
    const int lm = lane & 15;
    const int lk = (lane >> 4) << 3;
    const int r0 = (lane >> 4) << 2;

    // ---- L0: h1[32,512] = elu(Act[:, :256] @ W0^T + b0) ----
    f32x4 acc0[2][4];
    #pragma unroll
    for (int mt = 0; mt < 2; ++mt)
        #pragma unroll
        for (int nt = 0; nt < 4; ++nt) acc0[mt][nt] = {0.f, 0.f, 0.f, 0.f};
    #pragma unroll
    for (int kk = 0; kk < 8; ++kk) {
        const int ko = kk * 32 + lk;
        bf16x8 a0 = *(const bf16x8*)&sm.o.Act[lm * AS + ko];
        bf16x8 a1 = *(const bf16x8*)&sm.o.Act[(16 + lm) * AS + ko];
        #pragma unroll
        for (int nt = 0; nt < 4; ++nt) {
            const int n = wave * 64 + nt * 16 + lm;
            bf16x8 bb = *(const bf16x8*)&W0b[n * L_LAT + ko];
            acc0[0][nt] = MFMA(a0, bb, acc0[0][nt]);
            acc0[1][nt] = MFMA(a1, bb, acc0[1][nt]);
        }
    }
    __syncthreads();   // all Act (y_stage) reads done before overwrite
    #pragma unroll
    for (int nt = 0; nt < 4; ++nt) {
        const int col = wave * 64 + nt * 16 + lm;
        const float bv = b0[col];
        #pragma unroll
        for (int mt = 0; mt < 2; ++mt)
            #pragma unroll
            for (int r = 0; r < 4; ++r) {
                const int row = mt * 16 + r0 + r;
                sm.o.Act[row * AS + col] = f2bf(elu_f(acc0[mt][nt][r] + bv));
            }
    }
    __syncthreads();

    // ---- L1: h2[32,512] = elu(Act[:, :512] @ W1^T + b1) ----
    f32x4 acc1[2][4];
    #pragma unroll
    for (int mt = 0; mt < 2; ++mt)
        #pragma unroll
        for (int nt = 0; nt < 4; ++nt) acc1[mt][nt] = {0.f, 0.f, 0.f, 0.f};
    #pragma unroll
    for (int kk = 0; kk < 16; ++kk) {
        const int ko = kk * 32 + lk;
        bf16x8 a0 = *(const bf16x8*)&sm.o.Act[lm * AS + ko];
        bf16x8 a1 = *(const bf16x8*)&sm.o.Act[(16 + lm) * AS + ko];
        #pragma unroll
        for (int nt = 0; nt < 4; ++nt) {
            const int n = wave * 64 + nt * 16 + lm;
            bf16x8 bb = *(const bf16x8*)&W1b[n * W_HID + ko];
            acc1[0][nt] = MFMA(a0, bb, acc1[0][nt]);
            acc1[1][nt] = MFMA(a1, bb, acc1[1][nt]);
        }
    }
    __syncthreads();
    #pragma unroll
    for (int nt = 0; nt < 4; ++nt) {
        const int col = wave * 64 + nt * 16 + lm;
        const float bv = b1[col];
        #pragma unroll
        for (int mt = 0; mt < 2; ++mt)
            #pragma unroll
            for (int r = 0; r < 4; ++r) {
                const int row = mt * 16 + r0 + r;
                sm.o.Act[row * AS + col] = f2bf(elu_f(acc1[mt][nt][r] + bv));
            }
    }
    __syncthreads();

    // ---- L2: f[32,256] = Act[:, :512] @ W2^T + b2 ----
    f32x4 acc2[2][2];
    #pragma unroll
    for (int mt = 0; mt < 2; ++mt)
        #pragma unroll
        for (int nt = 0; nt < 2; ++nt) acc2[mt][nt] = {0.f, 0.f, 0.f, 0.f};
    #pragma unroll
    for (int kk = 0; kk < 16; ++kk) {
        const int ko = kk * 32 + lk;
        bf16x8 a0 = *(const bf16x8*)&sm.o.Act[lm * AS + ko];
        bf16x8 a1 = *(const bf16x8*)&sm.o.Act[(16 + lm) * AS + ko];
        #pragma unroll
        for (int nt = 0; nt < 2; ++nt) {
            const int n = wave * 32 + nt * 16 + lm;
            bf16x8 bb = *(const bf16x8*)&W2b[n * W_HID + ko];
            acc2[0][nt] = MFMA(a0, bb, acc2[0][nt]);
            acc2[1][nt] = MFMA(a1, bb, acc2[1][nt]);
        }
    }
    #pragma unroll
    for (int nt = 0; nt < 2; ++nt) {
        const int col = wave * 32 + nt * 16 + lm;
        const float bv = b2[col];
        #pragma unroll
        for (int mt = 0; mt < 2; ++mt)
            #pragma unroll
            for (int r = 0; r < 4; ++r) {
                const int row = mt * 16 + r0 + r;
                const float v = acc2[mt][nt][r] + bv;
                if (kdst) kdst[row * KS + col] = f2bf(v);
                else      sm.o.Y[row * YS + col] += (DT * BC6) * v;
            }
    }
    __syncthreads();
}

__device__ __forceinline__ void final_update(Smem& sm, int tid) {
    const int row = tid >> 4;
    const int cb  = (tid & 15) << 4;
    #pragma unroll
    for (int c = 0; c < 16; c += 4) {
        f32x4 acc = *(const f32x4*)&sm.o.Y[row * YS + cb + c];
        const float cfs[5] = {DT * BC1, DT * BC2, DT * BC3, DT * BC4, DT * BC5};
        #pragma unroll
        for (int j = 0; j < 5; ++j) {
            bf16x4 kv = *(const bf16x4*)&sm.o.Kb[j][row * KS + cb + c];
            acc[0] += cfs[j] * bf2f(kv[0]); acc[1] += cfs[j] * bf2f(kv[1]);
            acc[2] += cfs[j] * bf2f(kv[2]); acc[3] += cfs[j] * bf2f(kv[3]);
        }
        *(f32x4*)&sm.o.Y[row * YS + cb + c] = acc;
    }
}

__device__ void gru_step(Smem& sm, const float* __restrict__ x_seq, int t, int b0row,
                         int tid, int wave, int lane,
                         const bf16* __restrict__ Wih, const bf16* __restrict__ Whh,
                         const float* __restrict__ bias_c, const float* __restrict__ b_n) {
    // pre-pass: hx = [bf16(h) | bf16(x_t)]
    {
        const int row = tid >> 4;
        const int cb  = (tid & 15) << 4;
        #pragma unroll
        for (int c = 0; c < 16; c += 4) {
            f32x4 hv = *(const f32x4*)&sm.o.Y[row * YS + cb + c];
            bf16x4 o;
            o[0] = f2bf(hv[0]); o[1] = f2bf(hv[1]); o[2] = f2bf(hv[2]); o[3] = f2bf(hv[3]);
            *(bf16x4*)&sm.g.hx[row * XS + cb + c] = o;
        }
        #pragma unroll
        for (int e = tid; e < MB * F_IN; e += NTHR) {
            const int m = e >> 5, f = e & 31;
            sm.g.hx[m * XS + 256 + f] = f2bf(x_seq[((size_t)(b0row + m) * T_SEQ + t) * F_IN + f]);
        }
    }
    __syncthreads();

    // MFMA: accH = h @ W_hh^T slices, accX = x @ W_ih[:, :32]^T slices
    const int lm = lane & 15;
    const int lk = (lane >> 4) << 3;
    const int r0 = (lane >> 4) << 2;
    f32x4 accH[2][6], accX[2][6];
    #pragma unroll
    for (int mt = 0; mt < 2; ++mt)
        #pragma unroll
        for (int j = 0; j < 6; ++j) { accH[mt][j] = {0.f,0.f,0.f,0.f}; accX[mt][j] = {0.f,0.f,0.f,0.f}; }
    #pragma unroll
    for (int kk = 0; kk < 8; ++kk) {
        const int ko = kk * 32 + lk;
        bf16x8 a0 = *(const bf16x8*)&sm.g.hx[lm * XS + ko];
        bf16x8 a1 = *(const bf16x8*)&sm.g.hx[(16 + lm) * XS + ko];
        #pragma unroll
        for (int j = 0; j < 6; ++j) {
            const int n = wave * 96 + j * 16 + lm;
            bf16x8 bb = *(const bf16x8*)&Whh[n * L_LAT + ko];
            accH[0][j] = MFMA(a0, bb, accH[0][j]);
            accH[1][j] = MFMA(a1, bb, accH[1][j]);
        }
    }
    {
        bf16x8 a0 = *(const bf16x8*)&sm.g.hx[lm * XS + 256 + lk];
        bf16x8 a1 = *(const bf16x8*)&sm.g.hx[(16 + lm) * XS + 256 + lk];
        #pragma unroll
        for (int j = 0; j < 6; ++j) {
            const int n = wave * 96 + j * 16 + lm;
            bf16x8 bb = *(const bf16x8*)&Wih[n * 96 + lk];
            accX[0][j] = MFMA(a0, bb, accX[0][j]);
            accX[1][j] = MFMA(a1, bb, accX[1][j]);
        }
    }
    // dump (hhih disjoint from hx; no barrier needed before)
    #pragma unroll
    for (int j = 0; j < 6; ++j) {
        const int n = wave * 96 + j * 16 + lm;
        #pragma unroll
        for (int mt = 0; mt < 2; ++mt)
            #pragma unroll
            for (int r = 0; r < 4; ++r) {
                const int row = mt * 16 + r0 + r;
                if (n < 512) {
                    sm.g.hhih[row * GS + n] = f2bf(accH[mt][j][r] + accX[mt][j][r]);
                } else {
                    sm.g.hhih[row * GS + n]       = f2bf(accX[mt][j][r]);   // inn
                    sm.g.hhih[row * GS + n + 256] = f2bf(accH[mt][j][r]);   // hn
                }
            }
    }
    __syncthreads();

    // gates
    {
        const int row = tid >> 4;
        const int cb  = (tid & 15) << 4;
        const float* bc = bias_c + (size_t)sm.o.cty[row] * 768;
        #pragma unroll 4
        for (int c = 0; c < 16; ++c) {
            const int j = cb + c;
            const float Sr  = bf2f(sm.g.hhih[row * GS + j])        + bc[j];
            const float Sz  = bf2f(sm.g.hhih[row * GS + 256 + j])  + bc[256 + j];
            const float inn = bf2f(sm.g.hhih[row * GS + 512 + j])  + bc[512 + j];
            const float hn  = bf2f(sm.g.hhih[row * GS + 768 + j]);
            const float r = sigm_f(Sr), z = sigm_f(Sz);
            const float nn = tanh_fast(inn + r * (hn + b_n[j]));
            const float h = sm.o.Y[row * YS + j];
            sm.o.Y[row * YS + j] = nn + z * (h - nn);
        }
    }
    __syncthreads();
}

__global__ void __launch_bounds__(NTHR, 2)
k_main(const float* __restrict__ x_seq, const int* __restrict__ cidx,
       const float* __restrict__ b_n, const float* __restrict__ b0,
       const float* __restrict__ b1, const float* __restrict__ b2,
       const float* __restrict__ W_dec, const float* __restrict__ b_dec,
       const bf16* __restrict__ Wih, const bf16* __restrict__ Whh,
       const bf16* __restrict__ W0b, const bf16* __restrict__ W1b,
       const bf16* __restrict__ W2b, const float* __restrict__ bias_c,
       float* __restrict__ out, int H) {
    __shared__ Smem sm;
    const int tid = threadIdx.x, wave = tid >> 6, lane = tid & 63;
    const int b0row = blockIdx.x * MB;

    for (int i = tid; i < NT_OUT * L_LAT; i += NTHR) sm.o.Wdec[i] = W_dec[i];
    if (tid < NT_OUT) sm.o.bdec[tid] = b_dec[tid];
    if (tid < MB) sm.o.cty[tid] = cidx[b0row + tid];
    for (int i = tid; i < MB * YS; i += NTHR) sm.o.Y[i] = 0.f;
    __syncthreads();

    // ---- GRU encoder ----
    for (int t = 0; t < T_SEQ; ++t)
        gru_step(sm, x_seq, t, b0row, tid, wave, lane, Wih, Whh, bias_c, b_n);

    // ---- Neural ODE (Tsit5) + decode ----
    for (int u = 0; u < H; ++u) {
        for (int s = 0; s < SUBSTEPS; ++s) {
            build_stage<0>(sm, tid, TC1); __syncthreads();
            eval_f(sm, W0b, W1b, W2b, b0, b1, b2, wave, lane, sm.o.Kb[0]);
            build_stage<1>(sm, tid, TC2); __syncthreads();
            eval_f(sm, W0b, W1b, W2b, b0, b1, b2, wave, lane, sm.o.Kb[1]);
            build_stage<2>(sm, tid, TC3); __syncthreads();
            eval_f(sm, W0b, W1b, W2b, b0, b1, b2, wave, lane, sm.o.Kb[2]);
            build_stage<3>(sm, tid, TC4); __syncthreads();
            eval_f(sm, W0b, W1b, W2b, b0, b1, b2, wave, lane, sm.o.Kb[3]);
            build_stage<4>(sm, tid, TC5); __syncthreads();
            eval_f(sm, W0b, W1b, W2b, b0, b1, b2, wave, lane, sm.o.Kb[4]);
            build_stage<5>(sm, tid, TC6); __syncthreads();
            eval_f(sm, W0b, W1b, W2b, b0, b1, b2, wave, lane, nullptr);  // y += dt*BC6*k6
            final_update(sm, tid);                                        // y += dt*(BC1..BC5 . k1..k5)
            __syncthreads();
        }
        // decode at unit boundary
        if (tid < MB * NT_OUT) {
            const int m = tid >> 3, tt = tid & 7;
            float s = sm.o.bdec[tt];
            const float* wd = &sm.o.Wdec[tt * L_LAT];
            #pragma unroll 2
            for (int l = 0; l < L_LAT; l += 4) {
                f32x4 yv = *(const f32x4*)&sm.o.Y[m * YS + l];
                s += yv[0] * wd[l] + yv[1] * wd[l + 1] + yv[2] * wd[l + 2] + yv[3] * wd[l + 3];
            }
            out[((size_t)(b0row + m) * H + u) * NT_OUT + tt] = s;
        }
        // no barrier needed: next op only reads Y / writes Act
    }
}

__global__ void k_cvt(const float* __restrict__ s, bf16* __restrict__ d, int n) {
    int i = blockIdx.x * blockDim.x + threadIdx.x;
    const int stride = gridDim.x * blockDim.x;
    for (; i < n; i += stride) d[i] = (bf16)s[i];
}

__global__ void k_bias(const float* __restrict__ W_ih, const float* __restrict__ b_ih,
                       float* __restrict__ bias_c) {
    const int i = blockIdx.x * blockDim.x + threadIdx.x;
    if (i < C_CTY * 3 * L_LAT) {
        const int c = i / (3 * L_LAT), n = i - c * (3 * L_LAT);
        bias_c[i] = W_ih[n * (F_IN + C_CTY) + F_IN + c] + b_ih[n];
    }
}

extern "C" void kernel_launch(void* const* d_in, const int* in_sizes, int n_in,
                              void* d_out, int out_size, void* d_ws, size_t ws_size,
                              hipStream_t stream) {
    const float* x_seq = (const float*)d_in[0];
    const int*   cidx  = (const int*)d_in[1];
    // d_in[2] = horizon (derived from out_size instead)
    const float* W_ih  = (const float*)d_in[3];
    const float* W_hh  = (const float*)d_in[4];
    const float* b_ih  = (const float*)d_in[5];
    const float* b_n   = (const float*)d_in[6];
    const float* W0    = (const float*)d_in[7];
    const float* b0    = (const float*)d_in[8];
    const float* W1    = (const float*)d_in[9];
    const float* b1    = (const float*)d_in[10];
    const float* W2    = (const float*)d_in[11];
    const float* b2    = (const float*)d_in[12];
    const float* W_dec = (const float*)d_in[13];
    const float* b_dec = (const float*)d_in[14];
    float* out = (float*)d_out;
    const int H = out_size / (B_TOT * NT_OUT);

    char* ws = (char*)d_ws;
    bf16*  Wih_b  = (bf16*)(ws + 0);        // 768*96   -> 147,456 B
    bf16*  Whh_b  = (bf16*)(ws + 147456);   // 768*256  -> 393,216 B
    bf16*  W0b    = (bf16*)(ws + 540672);   // 512*256  -> 262,144 B
    bf16*  W1b    = (bf16*)(ws + 802816);   // 512*512  -> 524,288 B
    bf16*  W2b    = (bf16*)(ws + 1327104);  // 256*512  -> 262,144 B
    float* bias_c = (float*)(ws + 1589248); // 64*768 f32 -> 196,608 B

    k_cvt<<<288, 256, 0, stream>>>(W_ih, Wih_b, 768 * 96);
    k_cvt<<<768, 256, 0, stream>>>(W_hh, Whh_b, 768 * 256);
    k_cvt<<<512, 256, 0, stream>>>(W0, W0b, 512 * 256);
    k_cvt<<<1024, 256, 0, stream>>>(W1, W1b, 512 * 512);
    k_cvt<<<512, 256, 0, stream>>>(W2, W2b, 512 * 256);
    k_bias<<<(C_CTY * 3 * L_LAT + 255) / 256, 256, 0, stream>>>(W_ih, b_ih, bias_c);

    k_main<<<NBLK, NTHR, 0, stream>>>(x_seq, cidx, b_n, b0, b1, b2, W_dec, b_dec,
                                      Wih_b, Whh_b, W0b, W1b, W2b, bias_c, out, H);
}